// Round 17
// baseline (40.609 us; speedup 1.0000x reference)
//
#include <hip/hip_runtime.h>
#include <hip/hip_bf16.h>

#define NROW 4096      // 2B
#define HALFB 2048     // B
#define CDIM 1024
#define INV_T 2.0f     // 1/0.5
#define NB64 64        // NROW / 64
#define NTRI64 2080    // NB64*(NB64+1)/2
#define NT 8           // K-tiles of 128
#define RB 512         // bytes per row in fp4 (1024 * 4bit)
#define SCALE_E8M0 122 // 2^-5: data stored as x*32 in e2m1; scale applied on A and B

typedef __attribute__((ext_vector_type(4))) float f32x4;
typedef __attribute__((ext_vector_type(8))) int i32x8;

// round-to-nearest e2m1 encode of q (|q| clamped to 6)
__device__ __forceinline__ unsigned enc_fp4(float q) {
    const unsigned s = q < 0.f ? 8u : 0u;
    const float a = fabsf(q);
    unsigned m;
    if (a < 1.25f) {
        if (a < 0.25f)      m = 0;   // 0.0
        else if (a < 0.75f) m = 1;   // 0.5
        else                m = 2;   // 1.0
    } else if (a < 2.5f) {
        m = (a < 1.75f) ? 3u : 4u;   // 1.5 : 2
    } else {
        if (a < 3.5f)       m = 5;   // 3
        else if (a < 5.0f)  m = 6;   // 4
        else                m = 7;   // 6
    }
    return s | m;
}

// ---------------- Kernel 1: wave-per-row L2-normalize + fp4 pack (+ zero den/out) ----------------
// 1024 blocks x 4 waves; one row per wave -> no LDS, no __syncthreads.
__global__ __launch_bounds__(256) void normalize_kernel(
        const float* __restrict__ z1, const float* __restrict__ z2,
        unsigned short* __restrict__ zb4, float* __restrict__ den,
        float* __restrict__ out) {
    const int t = threadIdx.x;
    const int wave = t >> 6, lane = t & 63;
    const int b = blockIdx.x;
    const int row = b * 4 + wave;
    if (b < 16) den[b * 256 + t] = 0.f;           // 16*256 = 4096
    else if (b == 16 && t == 0) out[0] = 0.f;     // loss accumulates atomically
    const float* src = (row < HALFB) ? (z1 + (size_t)row * CDIM)
                                     : (z2 + (size_t)(row - HALFB) * CDIM);
    float4 v[4];
    float ss = 0.f;
    #pragma unroll
    for (int p = 0; p < 4; ++p) {
        v[p] = ((const float4*)src)[p * 64 + lane];
        ss += v[p].x * v[p].x + v[p].y * v[p].y + v[p].z * v[p].z + v[p].w * v[p].w;
    }
    #pragma unroll
    for (int off = 1; off < 64; off <<= 1) ss += __shfl_xor(ss, off);
    const float scale = 32.0f / fmaxf(sqrtf(ss), 1e-12f);
    #pragma unroll
    for (int p = 0; p < 4; ++p) {
        const unsigned c0 = enc_fp4(v[p].x * scale);
        const unsigned c1 = enc_fp4(v[p].y * scale);
        const unsigned c2 = enc_fp4(v[p].z * scale);
        const unsigned c3 = enc_fp4(v[p].w * scale);
        zb4[(size_t)row * 256 + p * 64 + lane] =
            (unsigned short)(c0 | (c1 << 4) | (c2 << 8) | (c3 << 12));
    }
}

// ---------------- Kernel 2: single-wave 64^2-tile triangle MX-fp4 GEMM ----------------
// 2080 blocks x 64 threads (ONE wave per block; ~8 blocks/CU). The point: with a
// single wave, global_load_lds -> ds_read ordering needs only the wave's own
// vmcnt -- NO s_barrier, NO drain-to-0. True counted pipeline (T4) that every
// multi-wave variant couldn't have (barrier forces vmcnt(0): R3/R11/R15 ledger).
// Per K-tile t: issue stage(t+1) [8 loads] -> s_waitcnt vmcnt(8) [stage(t)
// drained, stage(t+1) in flight across this whole compute phase] -> 8 ds_read
// + 16 mfma_scale fp4. LDS dbuf 2x8KB = 16KB.
// Swizzle (rule 21): 16B chunk c of row r holds global chunk c^((r>>1)&3)
// (pre-swizzled source, linear gload_lds dest; same XOR on ds_read). 16 l15-rows
// x same chunk -> 8 distinct (r&1,c) bank groups x 2 = 2-way alias = free (m136).
// Buffer-reuse safety: ds_reads of buf[t-1] complete before their MFMAs (compiler
// lgkmcnt) which precede iter t's stage issue in program order; asm "memory"
// clobber pins ds_read vs vmcnt ordering.
// Rule #20 / R8: b[4] regs, a JIT per m, acc compile-time indexed, no VGPR cap.
__global__ __launch_bounds__(64) void gemm_den_kernel(
        const unsigned char* __restrict__ zb4, float* __restrict__ den,
        float* __restrict__ pos) {
    __shared__ __align__(16) unsigned char As[2][64 * 64];
    __shared__ __align__(16) unsigned char Bs[2][64 * 64];

    // XCD swizzle (2080 = 8*260, bijective), then triangle decode (uniform SALU)
    const int orig = blockIdx.x;
    int swz = (orig & 7) * (NTRI64 / 8) + (orig >> 3);
    int bi = 0, rem = swz;
    while (rem >= NB64 - bi) { rem -= NB64 - bi; ++bi; }
    const int bj = bi + rem;
    const int i0 = bi * 64, j0 = bj * 64;
    const bool diag = (bi == bj);
    const bool is_pos = (bj == bi + 32);   // holds S[i, i+B] on its tile diagonal

    const int lane = threadIdx.x;

    f32x4 acc[4][4];
    #pragma unroll
    for (int m = 0; m < 4; m++)
        #pragma unroll
        for (int n = 0; n < 4; n++) acc[m][n] = (f32x4){0.f, 0.f, 0.f, 0.f};

    // staging geometry: one gload_lds = 16 rows x 64B (1KB); lane: row=lane>>2, chunk=lane&3
    const int srow = lane >> 2;                            // 0..15
    const int schunk = (lane & 3) ^ ((srow >> 1) & 3);     // pre-swizzled source chunk

    const int l15 = lane & 15, ks = lane >> 4;

    auto stage = [&](int buf, int t) {
        const int kb = t * 64;                             // K-tile byte offset in row
        #pragma unroll
        for (int c = 0; c < 4; ++c) {
            const int r0 = c * 16;                         // uniform row base 0..48
            const unsigned char* ga =
                zb4 + (size_t)(i0 + r0 + srow) * RB + kb + schunk * 16;
            __builtin_amdgcn_global_load_lds(
                (const __attribute__((address_space(1))) void*)ga,
                (__attribute__((address_space(3))) void*)(As[buf] + r0 * 64),
                16, 0, 0);
            // diag blocks: j0 == i0 -> same panel staged twice (uniform schedule)
            const unsigned char* gb =
                zb4 + (size_t)(j0 + r0 + srow) * RB + kb + schunk * 16;
            __builtin_amdgcn_global_load_lds(
                (const __attribute__((address_space(1))) void*)gb,
                (__attribute__((address_space(3))) void*)(Bs[buf] + r0 * 64),
                16, 0, 0);
        }
    };

    // prologue: stage K-tile 0 (8 loads in flight)
    stage(0, 0);

    #pragma unroll
    for (int t = 0; t < NT; ++t) {
        const int buf = t & 1;
        if (t + 1 < NT) {
            stage(buf ^ 1, t + 1);   // 16 outstanding
            asm volatile("s_waitcnt vmcnt(8)" ::: "memory");   // stage(t) done
        } else {
            asm volatile("s_waitcnt vmcnt(0)" ::: "memory");   // last tile
        }

        i32x8 b[4];
        #pragma unroll
        for (int n = 0; n < 4; ++n) {
            const int r = n * 16 + l15;
            const int slot = ks ^ ((r >> 1) & 3);
            const int4 w = *(const int4*)(Bs[buf] + r * 64 + slot * 16);
            b[n] = (i32x8){w.x, w.y, w.z, w.w, 0, 0, 0, 0};
        }
        __builtin_amdgcn_s_setprio(1);
        #pragma unroll
        for (int m = 0; m < 4; ++m) {
            const int r = m * 16 + l15;
            const int slot = ks ^ ((r >> 1) & 3);
            const int4 w = *(const int4*)(As[buf] + r * 64 + slot * 16);
            const i32x8 a = (i32x8){w.x, w.y, w.z, w.w, 0, 0, 0, 0};
            #pragma unroll
            for (int n = 0; n < 4; ++n)
                acc[m][n] = __builtin_amdgcn_mfma_scale_f32_16x16x128_f8f6f4(
                    a, b[n], acc[m][n],
                    4 /*cbsz: A=fp4*/, 4 /*blgp: B=fp4*/,
                    0, SCALE_E8M0, 0, SCALE_E8M0);
        }
        __builtin_amdgcn_s_setprio(0);
    }

    // ---- positives: tiles bj == bi+32 hold S[i, i+B] on their diagonal
    if (is_pos) {
        #pragma unroll
        for (int m = 0; m < 4; ++m) {
            #pragma unroll
            for (int r = 0; r < 4; ++r) {
                if (l15 == ks * 4 + r)
                    pos[i0 + m * 16 + l15] = acc[m][m][r];
            }
        }
    }

    // ---- epilogue: e = exp(2*s); row-sums -> den[i-panel]; col-sums -> den[j-panel]
    float cs[4] = {0.f, 0.f, 0.f, 0.f};
    #pragma unroll
    for (int m = 0; m < 4; ++m) {
        #pragma unroll
        for (int r = 0; r < 4; ++r) {
            float rs = 0.f;
            #pragma unroll
            for (int n = 0; n < 4; ++n) {
                const float e = __expf(INV_T * acc[m][n][r]);
                rs += e;
                cs[n] += e;
            }
            rs += __shfl_xor(rs, 1);
            rs += __shfl_xor(rs, 2);
            rs += __shfl_xor(rs, 4);
            rs += __shfl_xor(rs, 8);
            if (l15 == 0) {
                const int grow = i0 + m * 16 + ks * 4 + r;
                atomicAdd(&den[grow], rs);
            }
        }
    }
    if (!diag) {
        #pragma unroll
        for (int n = 0; n < 4; ++n) {
            float c = cs[n];
            c += __shfl_xor(c, 16);
            c += __shfl_xor(c, 32);
            if (lane < 16) {
                const int gcol = j0 + n * 16 + lane;
                atomicAdd(&den[gcol], c);
            }
        }
    }
}

// ---------------- Kernel 3: final loss, 16-block parallel ----------------
__global__ __launch_bounds__(256) void loss_kernel(
        const float* __restrict__ den, const float* __restrict__ pos,
        float* __restrict__ out) {
    const float E2 = 7.3890560989306495f;  // exp(2) = diagonal term
    const int tid = threadIdx.x;
    const int i = blockIdx.x * 256 + tid;
    float acc = INV_T * pos[i & (HALFB - 1)] - logf(den[i] - E2);
    #pragma unroll
    for (int off = 1; off < 64; off <<= 1) acc += __shfl_xor(acc, off);
    __shared__ float wsum[4];
    const int lane = tid & 63, wv = tid >> 6;
    if (lane == 0) wsum[wv] = acc;
    __syncthreads();
    if (tid == 0)
        atomicAdd(out, -(wsum[0] + wsum[1] + wsum[2] + wsum[3]) * (1.0f / NROW));
}

extern "C" void kernel_launch(void* const* d_in, const int* in_sizes, int n_in,
                              void* d_out, int out_size, void* d_ws, size_t ws_size,
                              hipStream_t stream) {
    const float* z1 = (const float*)d_in[0];
    const float* z2 = (const float*)d_in[1];
    float* out = (float*)d_out;

    unsigned short* zb4 = (unsigned short*)d_ws;                     // 2 MB (fp4)
    float* den = (float*)((char*)d_ws + (size_t)NROW * RB);          // 16 KB
    float* pos = den + NROW;                                         // 8 KB

    normalize_kernel<<<NROW / 4, 256, 0, stream>>>(z1, z2, zb4, den, out);
    gemm_den_kernel<<<NTRI64, 64, 0, stream>>>((const unsigned char*)zb4, den, pos);
    loss_kernel<<<NROW / 256, 256, 0, stream>>>(den, pos, out);
}

// Round 18
// 29.470 us; speedup vs baseline: 1.3780x; 1.3780x over previous
//
#include <hip/hip_runtime.h>
#include <hip/hip_bf16.h>

#define NROW 4096      // 2B
#define HALFB 2048     // B
#define CDIM 1024
#define INV_T 2.0f     // 1/0.5
#define NBLK 32        // NROW / 128
#define NTRI 528       // NBLK*(NBLK+1)/2
#define NT 8           // K-tiles of 128
#define RB 512         // bytes per row in fp4 (1024 * 4bit)
#define SCALE_E8M0 122 // 2^-5: data stored as x*32 in e2m1; scale applied on A and B

typedef __attribute__((ext_vector_type(4))) float f32x4;
typedef __attribute__((ext_vector_type(8))) int i32x8;

// round-to-nearest e2m1 encode of q (|q| clamped to 6)
__device__ __forceinline__ unsigned enc_fp4(float q) {
    const unsigned s = q < 0.f ? 8u : 0u;
    const float a = fabsf(q);
    unsigned m;
    if (a < 1.25f) {
        if (a < 0.25f)      m = 0;   // 0.0
        else if (a < 0.75f) m = 1;   // 0.5
        else                m = 2;   // 1.0
    } else if (a < 2.5f) {
        m = (a < 1.75f) ? 3u : 4u;   // 1.5 : 2
    } else {
        if (a < 3.5f)       m = 5;   // 3
        else if (a < 5.0f)  m = 6;   // 4
        else                m = 7;   // 6
    }
    return s | m;
}

// ---------------- Kernel 1: row L2-normalize + fp4(e2m1) pack (+ zero den/out) ----------------
__global__ __launch_bounds__(256) void normalize_kernel(
        const float* __restrict__ z1, const float* __restrict__ z2,
        unsigned short* __restrict__ zb4, float* __restrict__ den,
        float* __restrict__ out) {
    const int row = blockIdx.x;
    const int t = threadIdx.x;
    if (row < 16) den[row * 256 + t] = 0.f;       // NROW = 16*256
    else if (row == 16 && t == 0) out[0] = 0.f;   // loss accumulates atomically
    const float* src = (row < HALFB) ? (z1 + (size_t)row * CDIM)
                                     : (z2 + (size_t)(row - HALFB) * CDIM);
    float4 v = ((const float4*)src)[t];
    float ss = v.x * v.x + v.y * v.y + v.z * v.z + v.w * v.w;
    #pragma unroll
    for (int off = 1; off < 64; off <<= 1) ss += __shfl_xor(ss, off);
    __shared__ float wsum[4];
    const int lane = t & 63, wv = t >> 6;
    if (lane == 0) wsum[wv] = ss;
    __syncthreads();
    const float tot = wsum[0] + wsum[1] + wsum[2] + wsum[3];
    const float scale = 32.0f / fmaxf(sqrtf(tot), 1e-12f);
    const unsigned c0 = enc_fp4(v.x * scale);
    const unsigned c1 = enc_fp4(v.y * scale);
    const unsigned c2 = enc_fp4(v.z * scale);
    const unsigned c3 = enc_fp4(v.w * scale);
    zb4[(size_t)row * 256 + t] = (unsigned short)(c0 | (c1 << 4) | (c2 << 8) | (c3 << 12));
}

// ---------------- Kernel 2: upper-triangle MX-fp4 GEMM, DEPTH-2 counted pipeline ----------------
// R11 body, but the loop is a true T4 counted pipeline: triple-buffered LDS
// (3 x (8KB A + 8KB B) = 48KB), prologue stages tiles 0,1; iteration t does
//   vmcnt(4)  [drain stage(t)'s 4 loads/wave, keep stage(t+1)'s 4 in flight]
//   raw s_barrier  [all waves' stage(t) landed -> buf t%3 complete]
//   issue stage(t+2) -> ds_read buf[t%3] -> 16 MFMA
// The queue NEVER drains to 0 in the main loop (R11 drained every iter; that
// depth-1 pipeline gave stage latency only ~1 compute phase to land; depth-2
// gives it two). Race safety with ONE barrier/iter: buf[(t+2)%3] was last read
// at iter t-1; each wave's ds_reads land in regs before its MFMAs (compiler
// lgkmcnt) which precede barrier t; stage(t+2) issues after barrier t.
// Swizzle (rule 21) unchanged: chunk c of row r holds global chunk c^((r>>1)&3),
// pre-swizzled source + same XOR on ds_read; 2-way residual = free (m136).
// Rule #20 / R8: b[4] regs, a JIT per m, acc compile-time indexed; no fused tail
// (R12/R14: 80-VGPR cap + spill), no VGPR cap in launch_bounds.
__global__ __launch_bounds__(256) void gemm_den_kernel(
        const unsigned char* __restrict__ zb4, float* __restrict__ den,
        float* __restrict__ pos) {
    __shared__ __align__(16) unsigned char As[3][128 * 64];
    __shared__ __align__(16) unsigned char Bs[3][128 * 64];

    // XCD swizzle (528 = 8*66, bijective), then triangle decode
    const int orig = blockIdx.x;
    int swz = (orig & 7) * (NTRI / 8) + (orig >> 3);
    int bi = 0, rem = swz;
    while (rem >= NBLK - bi) { rem -= NBLK - bi; ++bi; }
    const int bj = bi + rem;
    const int i0 = bi * 128, j0 = bj * 128;
    const bool diag = (bi == bj);
    const bool is_pos = (bj == bi + 16);   // holds S[i, i+B] on its tile diagonal

    const int tid = threadIdx.x;
    const int wave = tid >> 6, lane = tid & 63;
    const int wr = wave >> 1, wc = wave & 1;

    f32x4 acc[4][4];
    #pragma unroll
    for (int m = 0; m < 4; m++)
        #pragma unroll
        for (int n = 0; n < 4; n++) acc[m][n] = (f32x4){0.f, 0.f, 0.f, 0.f};

    // staging geometry: one gload_lds = 16 rows x 64B; lane: row=lane>>2, chunk=lane&3
    const int srow = lane >> 2;                            // 0..15
    const int schunk = (lane & 3) ^ ((srow >> 1) & 3);     // pre-swizzled source chunk

    const int l15 = lane & 15, ks = lane >> 4;

    // 4 loads per wave per stage (2 for A + 2 for B)
    auto stage = [&](int buf, int t) {
        const int kb = t * 64;
        #pragma unroll
        for (int c = 0; c < 2; ++c) {
            const int r0 = wave * 32 + c * 16;             // wave-uniform row base
            const unsigned char* ga =
                zb4 + (size_t)(i0 + r0 + srow) * RB + kb + schunk * 16;
            __builtin_amdgcn_global_load_lds(
                (const __attribute__((address_space(1))) void*)ga,
                (__attribute__((address_space(3))) void*)(As[buf] + r0 * 64),
                16, 0, 0);
            // diag blocks: j0 == i0 -> same panel staged twice (uniform schedule)
            const unsigned char* gb =
                zb4 + (size_t)(j0 + r0 + srow) * RB + kb + schunk * 16;
            __builtin_amdgcn_global_load_lds(
                (const __attribute__((address_space(1))) void*)gb,
                (__attribute__((address_space(3))) void*)(Bs[buf] + r0 * 64),
                16, 0, 0);
        }
    };

    // prologue: two tiles in flight (8 loads/wave outstanding)
    stage(0, 0);
    stage(1, 1);

    #pragma unroll
    for (int t = 0; t < NT; ++t) {
        // drain stage(t) only; stage(t+1) stays in flight (never drain to 0 mid-loop)
        if (t + 1 < NT) asm volatile("s_waitcnt vmcnt(4)" ::: "memory");
        else            asm volatile("s_waitcnt vmcnt(0)" ::: "memory");
        __builtin_amdgcn_s_barrier();          // all waves' stage(t) landed
        __builtin_amdgcn_sched_barrier(0);

        const int buf = t % 3;                 // compile-time (loop fully unrolled)
        if (t + 2 < NT) stage((t + 2) % 3, t + 2);

        i32x8 b[4];
        #pragma unroll
        for (int n = 0; n < 4; ++n) {
            const int r = wc * 64 + n * 16 + l15;
            const int slot = ks ^ ((r >> 1) & 3);
            const int4 w = *(const int4*)(Bs[buf] + r * 64 + slot * 16);
            b[n] = (i32x8){w.x, w.y, w.z, w.w, 0, 0, 0, 0};
        }
        __builtin_amdgcn_s_setprio(1);
        #pragma unroll
        for (int m = 0; m < 4; ++m) {
            const int r = wr * 64 + m * 16 + l15;
            const int slot = ks ^ ((r >> 1) & 3);
            const int4 w = *(const int4*)(As[buf] + r * 64 + slot * 16);
            const i32x8 a = (i32x8){w.x, w.y, w.z, w.w, 0, 0, 0, 0};
            #pragma unroll
            for (int n = 0; n < 4; ++n)
                acc[m][n] = __builtin_amdgcn_mfma_scale_f32_16x16x128_f8f6f4(
                    a, b[n], acc[m][n],
                    4 /*cbsz: A=fp4*/, 4 /*blgp: B=fp4*/,
                    0, SCALE_E8M0, 0, SCALE_E8M0);
        }
        __builtin_amdgcn_s_setprio(0);
    }

    // ---- positives: tiles bj == bi+16 (bi<16) hold S[i, i+B] on their diagonal
    if (is_pos && wr == wc) {
        #pragma unroll
        for (int m = 0; m < 4; ++m) {
            #pragma unroll
            for (int r = 0; r < 4; ++r) {
                if (l15 == ks * 4 + r)
                    pos[i0 + wr * 64 + m * 16 + l15] = acc[m][m][r];
            }
        }
    }

    // ---- epilogue: e = exp(2*s); row-sums -> den[i-panel]; col-sums -> den[j-panel]
    float cs[4] = {0.f, 0.f, 0.f, 0.f};
    #pragma unroll
    for (int m = 0; m < 4; ++m) {
        #pragma unroll
        for (int r = 0; r < 4; ++r) {
            float rs = 0.f;
            #pragma unroll
            for (int n = 0; n < 4; ++n) {
                const float e = __expf(INV_T * acc[m][n][r]);
                rs += e;
                cs[n] += e;
            }
            rs += __shfl_xor(rs, 1);
            rs += __shfl_xor(rs, 2);
            rs += __shfl_xor(rs, 4);
            rs += __shfl_xor(rs, 8);
            if (l15 == 0) {
                const int grow = i0 + wr * 64 + m * 16 + ks * 4 + r;
                atomicAdd(&den[grow], rs);
            }
        }
    }
    if (!diag) {
        #pragma unroll
        for (int n = 0; n < 4; ++n) {
            float c = cs[n];
            c += __shfl_xor(c, 16);
            c += __shfl_xor(c, 32);
            if (lane < 16) {
                const int gcol = j0 + wc * 64 + n * 16 + lane;
                atomicAdd(&den[gcol], c);
            }
        }
    }
}

// ---------------- Kernel 3: final loss, 16-block parallel ----------------
__global__ __launch_bounds__(256) void loss_kernel(
        const float* __restrict__ den, const float* __restrict__ pos,
        float* __restrict__ out) {
    const float E2 = 7.3890560989306495f;  // exp(2) = diagonal term
    const int tid = threadIdx.x;
    const int i = blockIdx.x * 256 + tid;
    float acc = INV_T * pos[i & (HALFB - 1)] - logf(den[i] - E2);
    #pragma unroll
    for (int off = 1; off < 64; off <<= 1) acc += __shfl_xor(acc, off);
    __shared__ float wsum[4];
    const int lane = tid & 63, wv = tid >> 6;
    if (lane == 0) wsum[wv] = acc;
    __syncthreads();
    if (tid == 0)
        atomicAdd(out, -(wsum[0] + wsum[1] + wsum[2] + wsum[3]) * (1.0f / NROW));
}

extern "C" void kernel_launch(void* const* d_in, const int* in_sizes, int n_in,
                              void* d_out, int out_size, void* d_ws, size_t ws_size,
                              hipStream_t stream) {
    const float* z1 = (const float*)d_in[0];
    const float* z2 = (const float*)d_in[1];
    float* out = (float*)d_out;

    unsigned short* zb4 = (unsigned short*)d_ws;                     // 2 MB (fp4)
    float* den = (float*)((char*)d_ws + (size_t)NROW * RB);          // 16 KB
    float* pos = den + NROW;                                         // 8 KB

    normalize_kernel<<<NROW, 256, 0, stream>>>(z1, z2, zb4, den, out);
    gemm_den_kernel<<<NTRI, 256, 0, stream>>>((const unsigned char*)zb4, den, pos);
    loss_kernel<<<NROW / 256, 256, 0, stream>>>(den, pos, out);
}

// Round 20
// 29.301 us; speedup vs baseline: 1.3859x; 1.0058x over previous
//
#include <hip/hip_runtime.h>
#include <hip/hip_bf16.h>

#define NROW 4096      // 2B
#define HALFB 2048     // B
#define CDIM 1024
#define INV_T 2.0f     // 1/0.5
#define NBLK 32        // NROW / 128
#define NTRI 528       // NBLK*(NBLK+1)/2
#define NT 8           // K-tiles of 128
#define RB 512         // bytes per row in fp4 (1024 * 4bit)
#define SCALE_E8M0 122 // 2^-5: data stored as x*32 in e2m1; scale applied on A and B

typedef __attribute__((ext_vector_type(4))) float f32x4;
typedef __attribute__((ext_vector_type(8))) int i32x8;

// round-to-nearest e2m1 encode of q (|q| clamped to 6)
__device__ __forceinline__ unsigned enc_fp4(float q) {
    const unsigned s = q < 0.f ? 8u : 0u;
    const float a = fabsf(q);
    unsigned m;
    if (a < 1.25f) {
        if (a < 0.25f)      m = 0;   // 0.0
        else if (a < 0.75f) m = 1;   // 0.5
        else                m = 2;   // 1.0
    } else if (a < 2.5f) {
        m = (a < 1.75f) ? 3u : 4u;   // 1.5 : 2
    } else {
        if (a < 3.5f)       m = 5;   // 3
        else if (a < 5.0f)  m = 6;   // 4
        else                m = 7;   // 6
    }
    return s | m;
}

// ---------------- Kernel 1: row L2-normalize + fp4(e2m1) pack (+ zero den/out) ----------------
__global__ __launch_bounds__(256) void normalize_kernel(
        const float* __restrict__ z1, const float* __restrict__ z2,
        unsigned short* __restrict__ zb4, float* __restrict__ den,
        float* __restrict__ out) {
    const int row = blockIdx.x;
    const int t = threadIdx.x;
    if (row < 16) den[row * 256 + t] = 0.f;       // NROW = 16*256
    else if (row == 16 && t == 0) out[0] = 0.f;   // loss accumulates atomically
    const float* src = (row < HALFB) ? (z1 + (size_t)row * CDIM)
                                     : (z2 + (size_t)(row - HALFB) * CDIM);
    float4 v = ((const float4*)src)[t];
    float ss = v.x * v.x + v.y * v.y + v.z * v.z + v.w * v.w;
    #pragma unroll
    for (int off = 1; off < 64; off <<= 1) ss += __shfl_xor(ss, off);
    __shared__ float wsum[4];
    const int lane = t & 63, wv = t >> 6;
    if (lane == 0) wsum[wv] = ss;
    __syncthreads();
    const float tot = wsum[0] + wsum[1] + wsum[2] + wsum[3];
    const float scale = 32.0f / fmaxf(sqrtf(tot), 1e-12f);
    const unsigned c0 = enc_fp4(v.x * scale);
    const unsigned c1 = enc_fp4(v.y * scale);
    const unsigned c2 = enc_fp4(v.z * scale);
    const unsigned c3 = enc_fp4(v.w * scale);
    zb4[(size_t)row * 256 + t] = (unsigned short)(c0 | (c1 << 4) | (c2 << 8) | (c3 << 12));
}

// ---------------- Kernel 2: upper-triangle MX-fp4 GEMM, DEPTH-2 counted pipeline ----------------
// Final form (29.5us anchor). 528 blocks, 256 thr (4 waves 2x2, per-wave 64x64).
// Triple-buffered LDS; prologue stages tiles 0,1; iteration t: vmcnt(4) [drain
// stage(t), keep stage(t+1) in flight] -> raw s_barrier -> stage(t+2) -> ds_read
// -> 16 mfma_scale fp4 (uniform E8M0 2^-5 scale; operand-symmetric layout).
// Swizzle (rule 21): chunk c of row r holds global chunk c^((r>>1)&3), source
// pre-swizzle + same XOR on ds_read; 2-way residual bank alias = free (m136).
// Ledger (do not revisit): dbuf-128^2 / BK=256 / 8-wave / 4-phase / counted-256^2 /
// single-wave-64^2 / depth-2 (null) all <= neutral; fused cross-block tail ->
// 80-VGPR regalloc cap + acc spill (R12/R14); cooperative fusion -> graph-capture
// incompatible (R19). Rule #20: all acc indices compile-time.
__global__ __launch_bounds__(256) void gemm_den_kernel(
        const unsigned char* __restrict__ zb4, float* __restrict__ den,
        float* __restrict__ pos) {
    __shared__ __align__(16) unsigned char As[3][128 * 64];
    __shared__ __align__(16) unsigned char Bs[3][128 * 64];

    // XCD swizzle (528 = 8*66, bijective), then triangle decode
    const int orig = blockIdx.x;
    int swz = (orig & 7) * (NTRI / 8) + (orig >> 3);
    int bi = 0, rem = swz;
    while (rem >= NBLK - bi) { rem -= NBLK - bi; ++bi; }
    const int bj = bi + rem;
    const int i0 = bi * 128, j0 = bj * 128;
    const bool diag = (bi == bj);
    const bool is_pos = (bj == bi + 16);   // holds S[i, i+B] on its tile diagonal

    const int tid = threadIdx.x;
    const int wave = tid >> 6, lane = tid & 63;
    const int wr = wave >> 1, wc = wave & 1;

    f32x4 acc[4][4];
    #pragma unroll
    for (int m = 0; m < 4; m++)
        #pragma unroll
        for (int n = 0; n < 4; n++) acc[m][n] = (f32x4){0.f, 0.f, 0.f, 0.f};

    // staging geometry: one gload_lds = 16 rows x 64B; lane: row=lane>>2, chunk=lane&3
    const int srow = lane >> 2;                            // 0..15
    const int schunk = (lane & 3) ^ ((srow >> 1) & 3);     // pre-swizzled source chunk

    const int l15 = lane & 15, ks = lane >> 4;

    // 4 loads per wave per stage (2 for A + 2 for B)
    auto stage = [&](int buf, int t) {
        const int kb = t * 64;
        #pragma unroll
        for (int c = 0; c < 2; ++c) {
            const int r0 = wave * 32 + c * 16;             // wave-uniform row base
            const unsigned char* ga =
                zb4 + (size_t)(i0 + r0 + srow) * RB + kb + schunk * 16;
            __builtin_amdgcn_global_load_lds(
                (const __attribute__((address_space(1))) void*)ga,
                (__attribute__((address_space(3))) void*)(As[buf] + r0 * 64),
                16, 0, 0);
            // diag blocks: j0 == i0 -> same panel staged twice (uniform schedule)
            const unsigned char* gb =
                zb4 + (size_t)(j0 + r0 + srow) * RB + kb + schunk * 16;
            __builtin_amdgcn_global_load_lds(
                (const __attribute__((address_space(1))) void*)gb,
                (__attribute__((address_space(3))) void*)(Bs[buf] + r0 * 64),
                16, 0, 0);
        }
    };

    // prologue: two tiles in flight (8 loads/wave outstanding)
    stage(0, 0);
    stage(1, 1);

    #pragma unroll
    for (int t = 0; t < NT; ++t) {
        // drain stage(t) only; stage(t+1) stays in flight (never drain to 0 mid-loop)
        if (t + 1 < NT) asm volatile("s_waitcnt vmcnt(4)" ::: "memory");
        else            asm volatile("s_waitcnt vmcnt(0)" ::: "memory");
        __builtin_amdgcn_s_barrier();          // all waves' stage(t) landed
        __builtin_amdgcn_sched_barrier(0);

        const int buf = t % 3;                 // compile-time (loop fully unrolled)
        if (t + 2 < NT) stage((t + 2) % 3, t + 2);

        i32x8 b[4];
        #pragma unroll
        for (int n = 0; n < 4; ++n) {
            const int r = wc * 64 + n * 16 + l15;
            const int slot = ks ^ ((r >> 1) & 3);
            const int4 w = *(const int4*)(Bs[buf] + r * 64 + slot * 16);
            b[n] = (i32x8){w.x, w.y, w.z, w.w, 0, 0, 0, 0};
        }
        __builtin_amdgcn_s_setprio(1);
        #pragma unroll
        for (int m = 0; m < 4; ++m) {
            const int r = wr * 64 + m * 16 + l15;
            const int slot = ks ^ ((r >> 1) & 3);
            const int4 w = *(const int4*)(As[buf] + r * 64 + slot * 16);
            const i32x8 a = (i32x8){w.x, w.y, w.z, w.w, 0, 0, 0, 0};
            #pragma unroll
            for (int n = 0; n < 4; ++n)
                acc[m][n] = __builtin_amdgcn_mfma_scale_f32_16x16x128_f8f6f4(
                    a, b[n], acc[m][n],
                    4 /*cbsz: A=fp4*/, 4 /*blgp: B=fp4*/,
                    0, SCALE_E8M0, 0, SCALE_E8M0);
        }
        __builtin_amdgcn_s_setprio(0);
    }

    // ---- positives: tiles bj == bi+16 (bi<16) hold S[i, i+B] on their diagonal
    if (is_pos && wr == wc) {
        #pragma unroll
        for (int m = 0; m < 4; ++m) {
            #pragma unroll
            for (int r = 0; r < 4; ++r) {
                if (l15 == ks * 4 + r)
                    pos[i0 + wr * 64 + m * 16 + l15] = acc[m][m][r];
            }
        }
    }

    // ---- epilogue: e = exp(2*s); row-sums -> den[i-panel]; col-sums -> den[j-panel]
    float cs[4] = {0.f, 0.f, 0.f, 0.f};
    #pragma unroll
    for (int m = 0; m < 4; ++m) {
        #pragma unroll
        for (int r = 0; r < 4; ++r) {
            float rs = 0.f;
            #pragma unroll
            for (int n = 0; n < 4; ++n) {
                const float e = __expf(INV_T * acc[m][n][r]);
                rs += e;
                cs[n] += e;
            }
            rs += __shfl_xor(rs, 1);
            rs += __shfl_xor(rs, 2);
            rs += __shfl_xor(rs, 4);
            rs += __shfl_xor(rs, 8);
            if (l15 == 0) {
                const int grow = i0 + wr * 64 + m * 16 + ks * 4 + r;
                atomicAdd(&den[grow], rs);
            }
        }
    }
    if (!diag) {
        #pragma unroll
        for (int n = 0; n < 4; ++n) {
            float c = cs[n];
            c += __shfl_xor(c, 16);
            c += __shfl_xor(c, 32);
            if (lane < 16) {
                const int gcol = j0 + wc * 64 + n * 16 + lane;
                atomicAdd(&den[gcol], c);
            }
        }
    }
}

// ---------------- Kernel 3: final loss, 16-block parallel ----------------
__global__ __launch_bounds__(256) void loss_kernel(
        const float* __restrict__ den, const float* __restrict__ pos,
        float* __restrict__ out) {
    const float E2 = 7.3890560989306495f;  // exp(2) = diagonal term
    const int tid = threadIdx.x;
    const int i = blockIdx.x * 256 + tid;
    float acc = INV_T * pos[i & (HALFB - 1)] - logf(den[i] - E2);
    #pragma unroll
    for (int off = 1; off < 64; off <<= 1) acc += __shfl_xor(acc, off);
    __shared__ float wsum[4];
    const int lane = tid & 63, wv = tid >> 6;
    if (lane == 0) wsum[wv] = acc;
    __syncthreads();
    if (tid == 0)
        atomicAdd(out, -(wsum[0] + wsum[1] + wsum[2] + wsum[3]) * (1.0f / NROW));
}

extern "C" void kernel_launch(void* const* d_in, const int* in_sizes, int n_in,
                              void* d_out, int out_size, void* d_ws, size_t ws_size,
                              hipStream_t stream) {
    const float* z1 = (const float*)d_in[0];
    const float* z2 = (const float*)d_in[1];
    float* out = (float*)d_out;

    unsigned short* zb4 = (unsigned short*)d_ws;                     // 2 MB (fp4)
    float* den = (float*)((char*)d_ws + (size_t)NROW * RB);          // 16 KB
    float* pos = den + NROW;                                         // 8 KB

    normalize_kernel<<<NROW, 256, 0, stream>>>(z1, z2, zb4, den, out);
    gemm_den_kernel<<<NTRI, 256, 0, stream>>>((const unsigned char*)zb4, den, pos);
    loss_kernel<<<NROW / 256, 256, 0, stream>>>(den, pos, out);
}